// Round 7
// baseline (280.134 us; speedup 1.0000x reference)
//
#include <hip/hip_runtime.h>
#include <hip/hip_bf16.h>

#define KK 32
#define DD 128
#define NEGV (-1e9f)
#define SE 136   // LDS row stride in ushorts: 272 B, 16-B aligned, non-pow2 banks

typedef __attribute__((ext_vector_type(8))) short bf16x8;
typedef __attribute__((ext_vector_type(8))) unsigned short u16x8;
typedef __attribute__((ext_vector_type(4))) float f32x4;

__device__ __forceinline__ unsigned short f2bf(float f) {
    union { float f; unsigned u; } v; v.f = f;
    unsigned r = v.u + 0x7fffu + ((v.u >> 16) & 1u);   // RNE
    return (unsigned short)(r >> 16);
}
__device__ __forceinline__ float bf2f(unsigned short h) {
    union { unsigned u; float f; } v; v.u = ((unsigned)h) << 16;
    return v.f;
}
// packed f32x2 -> bf16x2 (v_cvt_pk_bf16_f32), RNE
__device__ __forceinline__ unsigned pk2(float x, float y) {
    union { __hip_bfloat162 h; unsigned u; } c;
    c.h = __float22bfloat162_rn(float2{x, y});
    return c.u;
}

// ---- prep: blocks [0,u2e_blocks) cast u2e fp32->bf16 (2048 els/block);
//      blocks [u2e_blocks, +192): W1 -> W1t bf16 [n][k], W2 -> W2t bf16 [n][k]
__global__ __launch_bounds__(256) void prep_kernel(
    const float* __restrict__ u2e, const float* __restrict__ W1, const float* __restrict__ W2,
    unsigned short* __restrict__ u2e_bf, unsigned short* __restrict__ W1t,
    unsigned short* __restrict__ W2t, const int u2e_blocks)
{
    const int b = blockIdx.x;
    if (b < u2e_blocks) {
        const long base = (long)b * 2048 + threadIdx.x * 8;
        const float4* s = (const float4*)(u2e + base);
        const float4 v0 = s[0], v1 = s[1];
        uint4 p;
        p.x = pk2(v0.x, v0.y); p.y = pk2(v0.z, v0.w);
        p.z = pk2(v1.x, v1.y); p.w = pk2(v1.z, v1.w);
        *(uint4*)(u2e_bf + base) = p;
    } else {
        const int id = (b - u2e_blocks) * 256 + threadIdx.x;   // 0..49151
        if (id < 256 * 128) {
            const int n = id >> 8, k = id & 255;
            W1t[id] = f2bf(W1[k * DD + n]);
        } else {
            const int j = id - 256 * 128;
            const int n = j >> 7, k = j & 127;
            W2t[j] = f2bf(W2[k * DD + n]);
        }
    }
}

template<bool BF>
__global__ __launch_bounds__(256, 3) void ppagg_mfma(
    const int* __restrict__ nodes, const int* __restrict__ neigh,
    const int* __restrict__ degrees, const float* __restrict__ u2e,
    const unsigned short* __restrict__ u2e_bf,
    const unsigned short* __restrict__ W1t, const unsigned short* __restrict__ W2t,
    const float* __restrict__ b1, const float* __restrict__ b2,
    const float* __restrict__ W3, const float* __restrict__ b3,
    float* __restrict__ out, const int Nn)
{
    __shared__ __align__(16) unsigned short s_eh[128 * SE];  // e-tile -> h1 -> h2 (34.8 KB)
    __shared__ __align__(16) unsigned short s_x[4 * DD];     // self vectors bf16 (MFMA broadcast)
    __shared__ float s_w3[DD];
    __shared__ float s_att[128];
    __shared__ int   s_idx[256];   // neighbor indices, both iters

    const int tid  = threadIdx.x;
    const int w    = tid >> 6;     // wave id = node owner in epilogue
    const int lane = tid & 63;
    const int ln   = lane & 15;
    const int q    = lane >> 4;    // quad

    if (tid < DD) s_w3[tid] = W3[tid];

    // ---- W1 fragments resident in registers (64 VGPRs); W2 frags reloaded per use ----
    // B-frag (16x16x32): B[k = q*8+j][n = ln]; W1t/W2t are [n][k] -> contiguous 16 B reads
    bf16x8 b1f[8][2];
    float b1c[2], b2c[2];
    const int c0 = w * 32 + ln;       // col owned, nt=0
    const int c1 = c0 + 16;           // col owned, nt=1
    #pragma unroll
    for (int kk = 0; kk < 8; ++kk) {
        b1f[kk][0] = *(const bf16x8*)(W1t + c0 * 256 + kk * 32 + q * 8);
        b1f[kk][1] = *(const bf16x8*)(W1t + c1 * 256 + kk * 32 + q * 8);
    }
    b1c[0] = b1[c0]; b1c[1] = b1[c1];
    b2c[0] = b2[c0]; b2c[1] = b2[c1];

    const int nb = blockIdx.x * 8;
    const int r  = tid & 127;      // staged row
    const int h  = tid >> 7;       // col half (0: 0..63, 1: 64..127)

    // ---- prologue: both iters' indices + self rows ----
    int idxA, idxB;
    {
        int ng0 = nb + (r >> 5);       if (ng0 >= Nn) ng0 = Nn - 1;
        int ng1 = nb + 4 + (r >> 5);   if (ng1 >= Nn) ng1 = Nn - 1;
        idxA = neigh[ng0 * KK + (r & 31)];
        idxB = neigh[ng1 * KK + (r & 31)];
    }
    float2 self0, self1;
    {
        int n0 = nb + w;       if (n0 >= Nn) n0 = Nn - 1;
        int n1 = nb + 4 + w;   if (n1 >= Nn) n1 = Nn - 1;
        self0 = *(const float2*)(u2e + (long)nodes[n0] * DD + lane * 2);
        self1 = *(const float2*)(u2e + (long)nodes[n1] * DD + lane * 2);
    }

    #pragma unroll
    for (int it = 0; it < 2; ++it) {
        const int gbase = nb + it * 4;   // rows 0..127 = (g=row>>5, k=row&31)
        const float2 selfv = it ? self1 : self0;
        const int myidx = it ? idxB : idxA;

        // ---------- stage: half-row per thread, straight copy (BF) or cvt (fp32 fallback) ----------
        {
            unsigned short* dst = s_eh + r * SE + h * 64;
            if (BF) {
                const uint4* src = (const uint4*)(u2e_bf + (long)myidx * DD + h * 64);
                #pragma unroll
                for (int c = 0; c < 8; ++c) *(uint4*)(dst + c * 8) = src[c];
            } else {
                const float4* src = (const float4*)(u2e + (long)myidx * DD + h * 64);
                #pragma unroll
                for (int c8 = 0; c8 < 8; ++c8) {
                    const float4 v0 = src[c8 * 2];
                    const float4 v1 = src[c8 * 2 + 1];
                    uint4 p;
                    p.x = pk2(v0.x, v0.y); p.y = pk2(v0.z, v0.w);
                    p.z = pk2(v1.x, v1.y); p.w = pk2(v1.z, v1.w);
                    *(uint4*)(dst + c8 * 8) = p;
                }
            }
            *(unsigned*)(s_x + w * DD + lane * 2) = pk2(selfv.x, selfv.y);
            if (it == 0 && h == 0) { s_idx[r] = idxA; s_idx[128 + r] = idxB; }
        }
        __syncthreads();   // B1: e-tile ready

        // ---------- layer 1: C[128x128] = concat(e, self)[128x256] x W1 ----------
        f32x4 acc[8][2];
        #pragma unroll
        for (int mt = 0; mt < 8; ++mt) {
            acc[mt][0] = (f32x4){0.f, 0.f, 0.f, 0.f};
            acc[mt][1] = (f32x4){0.f, 0.f, 0.f, 0.f};
        }
        #pragma unroll
        for (int kk = 0; kk < 4; ++kk) {              // e-half of the concat
            bf16x8 a[8];
            #pragma unroll
            for (int mt = 0; mt < 8; ++mt)
                a[mt] = *(const bf16x8*)(s_eh + (mt * 16 + ln) * SE + kk * 32 + q * 8);
            #pragma unroll
            for (int mt = 0; mt < 8; ++mt) {
                acc[mt][0] = __builtin_amdgcn_mfma_f32_16x16x32_bf16(a[mt], b1f[kk][0], acc[mt][0], 0, 0, 0);
                acc[mt][1] = __builtin_amdgcn_mfma_f32_16x16x32_bf16(a[mt], b1f[kk][1], acc[mt][1], 0, 0, 0);
            }
        }
        #pragma unroll
        for (int kk = 4; kk < 8; ++kk) {              // self-half: broadcast row (g = mt>>1)
            #pragma unroll
            for (int mt = 0; mt < 8; ++mt) {
                const bf16x8 a = *(const bf16x8*)(s_x + (mt >> 1) * DD + (kk - 4) * 32 + q * 8);
                acc[mt][0] = __builtin_amdgcn_mfma_f32_16x16x32_bf16(a, b1f[kk][0], acc[mt][0], 0, 0, 0);
                acc[mt][1] = __builtin_amdgcn_mfma_f32_16x16x32_bf16(a, b1f[kk][1], acc[mt][1], 0, 0, 0);
            }
        }
        __syncthreads();   // B2: all e-tile reads done; s_eh reused for h1

        // h1 = relu(acc + b1) -> bf16 -> s_eh (C-layout: row = mt*16+q*4+rr, col = w*32+nt*16+ln)
        #pragma unroll
        for (int mt = 0; mt < 8; ++mt)
            #pragma unroll
            for (int nt = 0; nt < 2; ++nt) {
                const int c = nt ? c1 : c0;
                #pragma unroll
                for (int rr = 0; rr < 4; rr += 2) {
                    const unsigned p = pk2(fmaxf(acc[mt][nt][rr]     + b1c[nt], 0.f),
                                           fmaxf(acc[mt][nt][rr + 1] + b1c[nt], 0.f));
                    const int row = mt * 16 + q * 4 + rr;
                    s_eh[row * SE + c]       = (unsigned short)(p & 0xffffu);
                    s_eh[(row + 1) * SE + c] = (unsigned short)(p >> 16);
                }
            }
        __syncthreads();   // B3: h1 ready

        // ---------- layer 2: C2[128x128] = h1 x W2 (W2 frags streamed from L2 in 2 K-halves) ----------
        f32x4 acc2[8][2];
        #pragma unroll
        for (int mt = 0; mt < 8; ++mt) {
            acc2[mt][0] = (f32x4){0.f, 0.f, 0.f, 0.f};
            acc2[mt][1] = (f32x4){0.f, 0.f, 0.f, 0.f};
        }
        #pragma unroll
        for (int kh = 0; kh < 2; ++kh) {
            bf16x8 b2h[2][2];
            #pragma unroll
            for (int kk = 0; kk < 2; ++kk) {
                b2h[kk][0] = *(const bf16x8*)(W2t + c0 * 128 + (kh * 2 + kk) * 32 + q * 8);
                b2h[kk][1] = *(const bf16x8*)(W2t + c1 * 128 + (kh * 2 + kk) * 32 + q * 8);
            }
            #pragma unroll
            for (int kk = 0; kk < 2; ++kk) {
                bf16x8 a[8];
                #pragma unroll
                for (int mt = 0; mt < 8; ++mt)
                    a[mt] = *(const bf16x8*)(s_eh + (mt * 16 + ln) * SE + (kh * 2 + kk) * 32 + q * 8);
                #pragma unroll
                for (int mt = 0; mt < 8; ++mt) {
                    acc2[mt][0] = __builtin_amdgcn_mfma_f32_16x16x32_bf16(a[mt], b2h[kk][0], acc2[mt][0], 0, 0, 0);
                    acc2[mt][1] = __builtin_amdgcn_mfma_f32_16x16x32_bf16(a[mt], b2h[kk][1], acc2[mt][1], 0, 0, 0);
                }
            }
        }
        __syncthreads();   // B4: h1 reads done

        // h2 = relu(acc2 + b2) -> bf16 -> s_eh
        #pragma unroll
        for (int mt = 0; mt < 8; ++mt)
            #pragma unroll
            for (int nt = 0; nt < 2; ++nt) {
                const int c = nt ? c1 : c0;
                #pragma unroll
                for (int rr = 0; rr < 4; rr += 2) {
                    const unsigned p = pk2(fmaxf(acc2[mt][nt][rr]     + b2c[nt], 0.f),
                                           fmaxf(acc2[mt][nt][rr + 1] + b2c[nt], 0.f));
                    const int row = mt * 16 + q * 4 + rr;
                    s_eh[row * SE + c]       = (unsigned short)(p & 0xffffu);
                    s_eh[(row + 1) * SE + c] = (unsigned short)(p >> 16);
                }
            }
        __syncthreads();   // B5: h2 ready

        // ---------- logits + masked softmax (threads 0..127; shfl within 32-groups) ----------
        if (tid < 128) {
            const int row = tid;
            const unsigned short* hp = s_eh + row * SE;
            float dot = 0.f;
            #pragma unroll
            for (int c8 = 0; c8 < 16; ++c8) {
                const u16x8 hv = *(const u16x8*)(hp + c8 * 8);
                #pragma unroll
                for (int j = 0; j < 8; ++j)
                    dot = fmaf(bf2f(hv[j]), s_w3[c8 * 8 + j], dot);
            }
            const float logit = dot + b3[0];
            int ng = gbase + (row >> 5);
            if (ng >= Nn) ng = Nn - 1;
            const int deg = degrees[ng];
            const float ml = ((row & 31) < deg) ? logit : NEGV;
            float mx = ml;
            #pragma unroll
            for (int off = 16; off > 0; off >>= 1) mx = fmaxf(mx, __shfl_xor(mx, off));
            const float e = __expf(ml - mx);
            float ssum = e;
            #pragma unroll
            for (int off = 16; off > 0; off >>= 1) ssum += __shfl_xor(ssum, off);
            s_att[row] = e / ssum;
        }
        __syncthreads();   // B6: s_att ready (h2 reads also done)

        // ---------- epilogue: aggregation from the L2-hot table ----------
        {
            const int ng = gbase + w;
            float ax = 0.f, ay = 0.f;
            #pragma unroll
            for (int k = 0; k < KK; ++k) {
                const float a    = s_att[w * KK + k];
                const int   ridx = s_idx[it * 128 + w * KK + k];
                if (BF) {
                    const unsigned pe = *(const unsigned*)(u2e_bf + (long)ridx * DD + lane * 2);
                    ax = fmaf(a, bf2f((unsigned short)(pe & 0xffffu)), ax);
                    ay = fmaf(a, bf2f((unsigned short)(pe >> 16)), ay);
                } else {
                    const float2 ev = *(const float2*)(u2e + (long)ridx * DD + lane * 2);
                    ax = fmaf(a, ev.x, ax);
                    ay = fmaf(a, ev.y, ay);
                }
            }
            if (ng < Nn) {
                const int deg = degrees[ng];
                float2 o;
                o.x = (deg > 0) ? 0.5f * (ax + selfv.x) : selfv.x;
                o.y = (deg > 0) ? 0.5f * (ay + selfv.y) : selfv.y;
                *(float2*)(out + (long)ng * DD + lane * 2) = o;
            }
        }
        // no trailing barrier: next iter's s_eh writes are ordered by B6 (last s_eh
        // readers = logits); s_att next written only after next iter's B5->softmax,
        // which every thread reaches only after finishing this epilogue (program order
        // + B1..B5 of next iter); s_idx written only at it==0's stage.
    }
}

extern "C" void kernel_launch(void* const* d_in, const int* in_sizes, int n_in,
                              void* d_out, int out_size, void* d_ws, size_t ws_size,
                              hipStream_t stream) {
    const int*   nodes   = (const int*)d_in[0];
    const int*   neigh   = (const int*)d_in[1];
    const int*   degrees = (const int*)d_in[2];
    const float* u2e     = (const float*)d_in[3];
    const float* W1      = (const float*)d_in[4];
    const float* b1      = (const float*)d_in[5];
    const float* W2      = (const float*)d_in[6];
    const float* b2      = (const float*)d_in[7];
    const float* W3      = (const float*)d_in[8];
    const float* b3      = (const float*)d_in[9];
    float* out = (float*)d_out;

    const int  Nn = in_sizes[0];          // 20000
    const long Vd = (long)in_sizes[3];    // V*D = 12,800,000

    unsigned short* W1t = (unsigned short*)d_ws;        // 64 KB
    unsigned short* W2t = W1t + 256 * 128;              // 32 KB
    unsigned short* u2e_bf = W2t + 128 * 128;           // V*D bf16 = 25.6 MB

    const size_t need_bf = (size_t)(256 * 128 + 128 * 128) * 2 + (size_t)Vd * 2;
    const bool use_bf = (ws_size >= need_bf) && (Vd % 2048 == 0);
    const int u2e_blocks = use_bf ? (int)(Vd / 2048) : 0;

    prep_kernel<<<u2e_blocks + 192, 256, 0, stream>>>(u2e, W1, W2, u2e_bf, W1t, W2t, u2e_blocks);

    const int grid = (Nn + 7) / 8;
    if (use_bf)
        ppagg_mfma<true><<<grid, 256, 0, stream>>>(nodes, neigh, degrees, u2e, u2e_bf,
                                                   W1t, W2t, b1, b2, W3, b3, out, Nn);
    else
        ppagg_mfma<false><<<grid, 256, 0, stream>>>(nodes, neigh, degrees, u2e, nullptr,
                                                    W1t, W2t, b1, b2, W3, b3, out, Nn);
}

// Round 8
// 216.624 us; speedup vs baseline: 1.2932x; 1.2932x over previous
//
#include <hip/hip_runtime.h>
#include <hip/hip_bf16.h>

#define KK 32
#define DD 128
#define NEGV (-1e9f)
#define SE 136   // LDS row stride in ushorts: 272 B, 16-B aligned, non-pow2 banks

typedef __attribute__((ext_vector_type(8))) short bf16x8;
typedef __attribute__((ext_vector_type(4))) float f32x4;

__device__ __forceinline__ unsigned short f2bf(float f) {
    union { float f; unsigned u; } v; v.f = f;
    unsigned r = v.u + 0x7fffu + ((v.u >> 16) & 1u);   // RNE
    return (unsigned short)(r >> 16);
}
__device__ __forceinline__ float bf2f(unsigned short h) {
    union { unsigned u; float f; } v; v.u = ((unsigned)h) << 16;
    return v.f;
}
// packed f32x2 -> bf16x2 (v_cvt_pk_bf16_f32), RNE
__device__ __forceinline__ unsigned pk2(float x, float y) {
    union { __hip_bfloat162 h; unsigned u; } c;
    c.h = __float22bfloat162_rn(float2{x, y});
    return c.u;
}

// ---- prep: blocks [0,u2e_blocks) cast u2e fp32->bf16 (2048 els/block);
//      blocks [u2e_blocks, +192): W1 -> W1t bf16 [n][k], W2 -> W2t bf16 [n][k]
__global__ __launch_bounds__(256) void prep_kernel(
    const float* __restrict__ u2e, const float* __restrict__ W1, const float* __restrict__ W2,
    unsigned short* __restrict__ u2e_bf, unsigned short* __restrict__ W1t,
    unsigned short* __restrict__ W2t, const int u2e_blocks)
{
    const int b = blockIdx.x;
    if (b < u2e_blocks) {
        const long base = (long)b * 2048 + threadIdx.x * 8;
        const float4* s = (const float4*)(u2e + base);
        const float4 v0 = s[0], v1 = s[1];
        uint4 p;
        p.x = pk2(v0.x, v0.y); p.y = pk2(v0.z, v0.w);
        p.z = pk2(v1.x, v1.y); p.w = pk2(v1.z, v1.w);
        *(uint4*)(u2e_bf + base) = p;
    } else {
        const int id = (b - u2e_blocks) * 256 + threadIdx.x;   // 0..49151
        if (id < 256 * 128) {
            const int n = id >> 8, k = id & 255;
            W1t[id] = f2bf(W1[k * DD + n]);
        } else {
            const int j = id - 256 * 128;
            const int n = j >> 7, k = j & 127;
            W2t[j] = f2bf(W2[k * DD + n]);
        }
    }
}

template<bool BF>
__global__ __launch_bounds__(256, 2) void ppagg_mfma(
    const int* __restrict__ nodes, const int* __restrict__ neigh,
    const int* __restrict__ degrees, const float* __restrict__ u2e,
    const unsigned short* __restrict__ u2e_bf,
    const unsigned short* __restrict__ W1t, const unsigned short* __restrict__ W2t,
    const float* __restrict__ b1, const float* __restrict__ b2,
    const float* __restrict__ W3, const float* __restrict__ b3,
    float* __restrict__ out, const int Nn)
{
    __shared__ __align__(16) unsigned short s_eh[128 * SE];  // e-tile -> h1 (34.8 KB)
    __shared__ __align__(16) unsigned short s_x[4 * DD];     // self vectors bf16 (MFMA broadcast)
    __shared__ float s_part[4][128];                          // per-wave logit partials (2 KB)
    __shared__ float s_att[128];
    __shared__ int   s_idx[256];                              // neighbor indices, both iters

    const int tid  = threadIdx.x;
    const int w    = tid >> 6;     // wave id = node owner in epilogue
    const int lane = tid & 63;
    const int ln   = lane & 15;
    const int q    = lane >> 4;    // quad

    // ---- weight fragments in registers (R3-proven allocation: 96 VGPRs, no spill) ----
    // B-frag (16x16x32): B[k = q*8+j][n = ln]; W1t/W2t are [n][k] -> contiguous 16 B reads
    bf16x8 b1f[8][2], b2f[4][2];
    float b1c[2], b2c[2], w3c[2];
    const int c0 = w * 32 + ln;       // owned col, nt=0
    const int c1 = c0 + 16;           // owned col, nt=1
    #pragma unroll
    for (int kk = 0; kk < 8; ++kk) {
        b1f[kk][0] = *(const bf16x8*)(W1t + c0 * 256 + kk * 32 + q * 8);
        b1f[kk][1] = *(const bf16x8*)(W1t + c1 * 256 + kk * 32 + q * 8);
    }
    #pragma unroll
    for (int kk = 0; kk < 4; ++kk) {
        b2f[kk][0] = *(const bf16x8*)(W2t + c0 * 128 + kk * 32 + q * 8);
        b2f[kk][1] = *(const bf16x8*)(W2t + c1 * 128 + kk * 32 + q * 8);
    }
    b1c[0] = b1[c0]; b1c[1] = b1[c1];
    b2c[0] = b2[c0]; b2c[1] = b2[c1];
    w3c[0] = W3[c0]; w3c[1] = W3[c1];

    const int nb = blockIdx.x * 8;
    const int r  = tid & 127;      // staged row
    const int h  = tid >> 7;       // col half (0: 0..63, 1: 64..127)

    // ---- prologue: both iters' indices + self rows ----
    int idxA, idxB;
    {
        int ng0 = nb + (r >> 5);       if (ng0 >= Nn) ng0 = Nn - 1;
        int ng1 = nb + 4 + (r >> 5);   if (ng1 >= Nn) ng1 = Nn - 1;
        idxA = neigh[ng0 * KK + (r & 31)];
        idxB = neigh[ng1 * KK + (r & 31)];
    }
    float2 self0, self1;
    {
        int n0 = nb + w;       if (n0 >= Nn) n0 = Nn - 1;
        int n1 = nb + 4 + w;   if (n1 >= Nn) n1 = Nn - 1;
        self0 = *(const float2*)(u2e + (long)nodes[n0] * DD + lane * 2);
        self1 = *(const float2*)(u2e + (long)nodes[n1] * DD + lane * 2);
    }

    #pragma unroll
    for (int it = 0; it < 2; ++it) {
        const int gbase = nb + it * 4;   // rows 0..127 = (g=row>>5, k=row&31)
        const float2 selfv = it ? self1 : self0;
        const int myidx = it ? idxB : idxA;

        // ---------- stage: half-row per thread (128 B = one cache line) ----------
        {
            unsigned short* dst = s_eh + r * SE + h * 64;
            if (BF) {
                const uint4* src = (const uint4*)(u2e_bf + (long)myidx * DD + h * 64);
                #pragma unroll
                for (int c = 0; c < 8; ++c) *(uint4*)(dst + c * 8) = src[c];
            } else {
                const float4* src = (const float4*)(u2e + (long)myidx * DD + h * 64);
                #pragma unroll
                for (int c8 = 0; c8 < 8; ++c8) {
                    const float4 v0 = src[c8 * 2];
                    const float4 v1 = src[c8 * 2 + 1];
                    uint4 p;
                    p.x = pk2(v0.x, v0.y); p.y = pk2(v0.z, v0.w);
                    p.z = pk2(v1.x, v1.y); p.w = pk2(v1.z, v1.w);
                    *(uint4*)(dst + c8 * 8) = p;
                }
            }
            *(unsigned*)(s_x + w * DD + lane * 2) = pk2(selfv.x, selfv.y);
            if (it == 0 && h == 0) { s_idx[r] = idxA; s_idx[128 + r] = idxB; }
        }
        __syncthreads();   // B1: e-tile ready

        // ---------- layer 1: C[128x128] = concat(e, self)[128x256] x W1 ----------
        f32x4 acc[8][2];
        #pragma unroll
        for (int mt = 0; mt < 8; ++mt) {
            acc[mt][0] = (f32x4){0.f, 0.f, 0.f, 0.f};
            acc[mt][1] = (f32x4){0.f, 0.f, 0.f, 0.f};
        }
        #pragma unroll
        for (int kk = 0; kk < 4; ++kk) {              // e-half of the concat
            bf16x8 a[8];
            #pragma unroll
            for (int mt = 0; mt < 8; ++mt)
                a[mt] = *(const bf16x8*)(s_eh + (mt * 16 + ln) * SE + kk * 32 + q * 8);
            #pragma unroll
            for (int mt = 0; mt < 8; ++mt) {
                acc[mt][0] = __builtin_amdgcn_mfma_f32_16x16x32_bf16(a[mt], b1f[kk][0], acc[mt][0], 0, 0, 0);
                acc[mt][1] = __builtin_amdgcn_mfma_f32_16x16x32_bf16(a[mt], b1f[kk][1], acc[mt][1], 0, 0, 0);
            }
        }
        #pragma unroll
        for (int kk = 4; kk < 8; ++kk) {              // self-half: broadcast row (g = mt>>1)
            #pragma unroll
            for (int mt = 0; mt < 8; ++mt) {
                const bf16x8 a = *(const bf16x8*)(s_x + (mt >> 1) * DD + (kk - 4) * 32 + q * 8);
                acc[mt][0] = __builtin_amdgcn_mfma_f32_16x16x32_bf16(a, b1f[kk][0], acc[mt][0], 0, 0, 0);
                acc[mt][1] = __builtin_amdgcn_mfma_f32_16x16x32_bf16(a, b1f[kk][1], acc[mt][1], 0, 0, 0);
            }
        }
        __syncthreads();   // B2: all e-tile reads done; s_eh reused for h1

        // h1 = relu(acc + b1) -> bf16 -> s_eh (C-layout: row = mt*16+q*4+rr, col = c0/c1)
        #pragma unroll
        for (int mt = 0; mt < 8; ++mt)
            #pragma unroll
            for (int nt = 0; nt < 2; ++nt) {
                const int c = nt ? c1 : c0;
                #pragma unroll
                for (int rr = 0; rr < 4; rr += 2) {
                    const unsigned p = pk2(fmaxf(acc[mt][nt][rr]     + b1c[nt], 0.f),
                                           fmaxf(acc[mt][nt][rr + 1] + b1c[nt], 0.f));
                    const int row = mt * 16 + q * 4 + rr;
                    s_eh[row * SE + c]       = (unsigned short)(p & 0xffffu);
                    s_eh[(row + 1) * SE + c] = (unsigned short)(p >> 16);
                }
            }
        __syncthreads();   // B3: h1 ready

        // ---------- layer 2 + fused logit: h2 never touches LDS ----------
        f32x4 acc2[8][2];
        #pragma unroll
        for (int mt = 0; mt < 8; ++mt) {
            acc2[mt][0] = (f32x4){0.f, 0.f, 0.f, 0.f};
            acc2[mt][1] = (f32x4){0.f, 0.f, 0.f, 0.f};
        }
        #pragma unroll
        for (int kk = 0; kk < 4; ++kk) {
            bf16x8 a[8];
            #pragma unroll
            for (int mt = 0; mt < 8; ++mt)
                a[mt] = *(const bf16x8*)(s_eh + (mt * 16 + ln) * SE + kk * 32 + q * 8);
            #pragma unroll
            for (int mt = 0; mt < 8; ++mt) {
                acc2[mt][0] = __builtin_amdgcn_mfma_f32_16x16x32_bf16(a[mt], b2f[kk][0], acc2[mt][0], 0, 0, 0);
                acc2[mt][1] = __builtin_amdgcn_mfma_f32_16x16x32_bf16(a[mt], b2f[kk][1], acc2[mt][1], 0, 0, 0);
            }
        }
        // per-thread logit partials: p[rr] = relu(h2[c0])*w3[c0] + relu(h2[c1])*w3[c1],
        // reduced over the 16-lane col group (lanes q*16 .. q*16+15)
        #pragma unroll
        for (int mt = 0; mt < 8; ++mt) {
            float p[4];
            #pragma unroll
            for (int rr = 0; rr < 4; ++rr) {
                const float h0 = fmaxf(acc2[mt][0][rr] + b2c[0], 0.f);
                const float h1v = fmaxf(acc2[mt][1][rr] + b2c[1], 0.f);
                p[rr] = fmaf(h0, w3c[0], h1v * w3c[1]);
            }
            #pragma unroll
            for (int off = 1; off < 16; off <<= 1) {
                #pragma unroll
                for (int rr = 0; rr < 4; ++rr) p[rr] += __shfl_xor(p[rr], off);
            }
            if (ln == 0) {
                const int row0 = mt * 16 + q * 4;
                #pragma unroll
                for (int rr = 0; rr < 4; ++rr) s_part[w][row0 + rr] = p[rr];
            }
        }
        __syncthreads();   // B4: partials ready (also covers last h1 reads)

        // ---------- masked softmax (threads 0..127; shfl within 32-groups) ----------
        if (tid < 128) {
            const int row = tid;
            const float logit = s_part[0][row] + s_part[1][row] + s_part[2][row] + s_part[3][row] + b3[0];
            int ng = gbase + (row >> 5);
            if (ng >= Nn) ng = Nn - 1;
            const int deg = degrees[ng];
            const float ml = ((row & 31) < deg) ? logit : NEGV;
            float mx = ml;
            #pragma unroll
            for (int off = 16; off > 0; off >>= 1) mx = fmaxf(mx, __shfl_xor(mx, off));
            const float e = __expf(ml - mx);
            float ssum = e;
            #pragma unroll
            for (int off = 16; off > 0; off >>= 1) ssum += __shfl_xor(ssum, off);
            s_att[row] = e / ssum;
        }
        __syncthreads();   // B5: s_att ready

        // ---------- epilogue: aggregation from the L2-hot table ----------
        {
            const int ng = gbase + w;
            float ax = 0.f, ay = 0.f;
            #pragma unroll
            for (int k = 0; k < KK; ++k) {
                const float a    = s_att[w * KK + k];
                const int   ridx = s_idx[it * 128 + w * KK + k];
                if (BF) {
                    const unsigned pe = *(const unsigned*)(u2e_bf + (long)ridx * DD + lane * 2);
                    ax = fmaf(a, bf2f((unsigned short)(pe & 0xffffu)), ax);
                    ay = fmaf(a, bf2f((unsigned short)(pe >> 16)), ay);
                } else {
                    const float2 ev = *(const float2*)(u2e + (long)ridx * DD + lane * 2);
                    ax = fmaf(a, ev.x, ax);
                    ay = fmaf(a, ev.y, ay);
                }
            }
            if (ng < Nn) {
                const int deg = degrees[ng];
                float2 o;
                o.x = (deg > 0) ? 0.5f * (ax + selfv.x) : selfv.x;
                o.y = (deg > 0) ? 0.5f * (ay + selfv.y) : selfv.y;
                *(float2*)(out + (long)ng * DD + lane * 2) = o;
            }
        }
        // no trailing barrier: next iter's s_eh writes follow B1(it+1)? -- ordering:
        // epilogue reads s_att/s_idx/global only; next writers of s_att (next B4->B5)
        // and s_eh (next stage, which any thread reaches only after this epilogue in
        // program order, and cross-thread via B1..B5 of the next iteration).
    }
}

extern "C" void kernel_launch(void* const* d_in, const int* in_sizes, int n_in,
                              void* d_out, int out_size, void* d_ws, size_t ws_size,
                              hipStream_t stream) {
    const int*   nodes   = (const int*)d_in[0];
    const int*   neigh   = (const int*)d_in[1];
    const int*   degrees = (const int*)d_in[2];
    const float* u2e     = (const float*)d_in[3];
    const float* W1      = (const float*)d_in[4];
    const float* b1      = (const float*)d_in[5];
    const float* W2      = (const float*)d_in[6];
    const float* b2      = (const float*)d_in[7];
    const float* W3      = (const float*)d_in[8];
    const float* b3      = (const float*)d_in[9];
    float* out = (float*)d_out;

    const int  Nn = in_sizes[0];          // 20000
    const long Vd = (long)in_sizes[3];    // V*D = 12,800,000

    unsigned short* W1t = (unsigned short*)d_ws;        // 64 KB
    unsigned short* W2t = W1t + 256 * 128;              // 32 KB
    unsigned short* u2e_bf = W2t + 128 * 128;           // V*D bf16 = 25.6 MB

    const size_t need_bf = (size_t)(256 * 128 + 128 * 128) * 2 + (size_t)Vd * 2;
    const bool use_bf = (ws_size >= need_bf) && (Vd % 2048 == 0);
    const int u2e_blocks = use_bf ? (int)(Vd / 2048) : 0;

    prep_kernel<<<u2e_blocks + 192, 256, 0, stream>>>(u2e, W1, W2, u2e_bf, W1t, W2t, u2e_blocks);

    const int grid = (Nn + 7) / 8;
    if (use_bf)
        ppagg_mfma<true><<<grid, 256, 0, stream>>>(nodes, neigh, degrees, u2e, u2e_bf,
                                                   W1t, W2t, b1, b2, W3, b3, out, Nn);
    else
        ppagg_mfma<false><<<grid, 256, 0, stream>>>(nodes, neigh, degrees, u2e, nullptr,
                                                    W1t, W2t, b1, b2, W3, b3, out, Nn);
}